// Round 8
// baseline (397.694 us; speedup 1.0000x reference)
//
#include <hip/hip_runtime.h>
#include <hip/hip_bf16.h>
#include <stdint.h>

#define N 4096
#define BM 128
#define BN 128
#define BK 64      // bf16 K-tile (gemm_pv)
#define BK8 128    // fp8 K-tile (gemm_sym)
#define PM 256     // gemm_pv block rows
#define PN 128     // gemm_pv block cols

typedef __hip_bfloat16 bf16;
typedef __attribute__((ext_vector_type(8))) __bf16 bfrag;   // 8 bf16 (MFMA A/B operand)
typedef __attribute__((ext_vector_type(4))) float floatx4;  // MFMA C/D operand
typedef __attribute__((ext_vector_type(8))) int i32x8;      // 32 fp8 (f8f6f4 A/B operand)
typedef __attribute__((ext_vector_type(4))) int i32x4;

// ---------------------------------------------------------------------------
// async global -> LDS, 16B per lane (global_load_lds_dwordx4)
// ---------------------------------------------------------------------------
__device__ __forceinline__ void gld_lds16(const void* g, void* l) {
    __builtin_amdgcn_global_load_lds(
        (const __attribute__((address_space(1))) void*)g,
        (__attribute__((address_space(3))) void*)l, 16, 0, 0);
}

__device__ __forceinline__ unsigned short f2bf(float x) {
    __hip_bfloat16 h = __float2bfloat16(x);
    return *(unsigned short*)&h;
}

// ---------------------------------------------------------------------------
// Kernel 1: xb = bf16(in * 1/64)  (for gemm_pv's B operand)
//           x8 = fp8_e4m3(in)     (UNSCALED; exact 1/4096 applied via the
//                                  MFMA e8m0 scale operands, 2^-6 each side)
// blocks 0..15 also zero rowsum (replaces a memset dispatch).
// ---------------------------------------------------------------------------
__global__ __launch_bounds__(256) void cvt_scale(const float* __restrict__ in,
                                                 unsigned short* __restrict__ xb,
                                                 uint8_t* __restrict__ x8,
                                                 float* __restrict__ rowsum) {
    if (blockIdx.x < 16) rowsum[blockIdx.x * 256 + threadIdx.x] = 0.f;
    const long i = ((long)blockIdx.x * 256 + threadIdx.x) * 8;
    float4 a = *(const float4*)(in + i);
    float4 b = *(const float4*)(in + i + 4);
    const float sc = 0.015625f;  // 1/64 = 1/sqrt(4096)
    float v[8] = {a.x, a.y, a.z, a.w, b.x, b.y, b.z, b.w};
    alignas(16) unsigned short r[8];
#pragma unroll
    for (int k = 0; k < 8; ++k) r[k] = f2bf(v[k] * sc);
    *(uint4*)(xb + i) = *(const uint4*)r;

    int p0 = __builtin_amdgcn_cvt_pk_fp8_f32(v[0], v[1], 0, false);
    p0     = __builtin_amdgcn_cvt_pk_fp8_f32(v[2], v[3], p0, true);
    int p1 = __builtin_amdgcn_cvt_pk_fp8_f32(v[4], v[5], 0, false);
    p1     = __builtin_amdgcn_cvt_pk_fp8_f32(v[6], v[7], p1, true);
    int2 pk; pk.x = p0; pk.y = p1;
    *(int2*)(x8 + i) = pk;
}

// ---------------------------------------------------------------------------
// Kernel 2 (gemm_sym): E = exp(mask(x x^T)) -- EXACT R6-verified kernel
// (fp8 e4m3 at BK=128, 32 iterations, triangular 528-block grid, 512
// threads, 2x4 wave grid; passed at absmax 3.8e-6).
// ---------------------------------------------------------------------------
__global__ __launch_bounds__(512) void gemm_sym(const uint8_t* __restrict__ X8,
                                                unsigned short* __restrict__ E,
                                                float* __restrict__ rowsum) {
    __shared__ __align__(16) char smem[32768];
    uint8_t* As = (uint8_t*)smem;            // [128 rows][128 B] = 16 KB
    uint8_t* Bs = (uint8_t*)(smem + 16384);  // 16 KB

    const int t    = threadIdx.x;
    const int lane = t & 63;
    const int wave = t >> 6;      // 0..7
    const int wm   = wave >> 2;   // 0..1  (64-row strip)
    const int wn   = wave & 3;    // 0..3  (32-col strip)

    const int b = blockIdx.x;
    int I = (int)((sqrtf((float)(8 * b + 1)) - 1.0f) * 0.5f);
    if ((I + 1) * (I + 2) / 2 <= b) ++I;
    if (I * (I + 1) / 2 > b) --I;
    const int Jb = b - I * (I + 1) / 2;
    const int bm = I * BM;
    const int bn = Jb * BM;
    const bool diag = (I == Jb);

    floatx4 acc[4][2] = {};

    const int srow = t >> 3;                    // 0..63 (+64*i)
    const int skb  = (t & 7) ^ (srow & 7);
    const uint8_t* Ag = X8 + (long)(bm + srow) * N + skb * 16;
    const uint8_t* Bg = X8 + (long)(bn + srow) * N + skb * 16;
    uint8_t* Asl = As + t * 16;
    uint8_t* Bsl = Bs + t * 16;

    for (int k0 = 0; k0 < N; k0 += BK8) {
#pragma unroll
        for (int i = 0; i < 2; ++i) {
            gld_lds16(Ag + (long)i * 64 * N + k0, Asl + i * 8192);
            gld_lds16(Bg + (long)i * 64 * N + k0, Bsl + i * 8192);
        }
        __syncthreads();

        const int l15 = lane & 15;
        const int l7  = lane & 7;
        const int q   = lane >> 4;
        i32x8 af[4], bfr[2];
#pragma unroll
        for (int i = 0; i < 4; ++i) {
            const int row = wm * 64 + i * 16 + l15;
            i32x4 lo = *(const i32x4*)&As[(row * 8 + ((2 * q) ^ l7)) * 16];
            i32x4 hi = *(const i32x4*)&As[(row * 8 + ((2 * q + 1) ^ l7)) * 16];
            af[i] = (i32x8){lo.x, lo.y, lo.z, lo.w, hi.x, hi.y, hi.z, hi.w};
        }
#pragma unroll
        for (int j = 0; j < 2; ++j) {
            const int row = wn * 32 + j * 16 + l15;
            i32x4 lo = *(const i32x4*)&Bs[(row * 8 + ((2 * q) ^ l7)) * 16];
            i32x4 hi = *(const i32x4*)&Bs[(row * 8 + ((2 * q + 1) ^ l7)) * 16];
            bfr[j] = (i32x8){lo.x, lo.y, lo.z, lo.w, hi.x, hi.y, hi.z, hi.w};
        }
#pragma unroll
        for (int i = 0; i < 4; ++i)
#pragma unroll
            for (int j = 0; j < 2; ++j)
                acc[i][j] = __builtin_amdgcn_mfma_scale_f32_16x16x128_f8f6f4(
                    af[i], bfr[j], acc[i][j],
                    0, 0,               // A,B both fp8 e4m3
                    0, 0x79797979,      // A scale: e8m0 121 = 2^-6
                    0, 0x79797979);     // B scale: 2^-6 (product 1/4096)
        __syncthreads();
    }

    const int l15  = lane & 15;
    const int q    = lane >> 4;
    const int col0 = bn + wn * 32 + l15;
    const int row0 = bm + wm * 64 + q * 4;

#pragma unroll
    for (int i = 0; i < 4; ++i) {
#pragma unroll
        for (int r = 0; r < 4; ++r) {
            const int row = row0 + i * 16 + r;
            float rs = 0.f;
#pragma unroll
            for (int j = 0; j < 2; ++j) {
                const int col = col0 + j * 16;
                float e = (row == col) ? 0.f : __expf(acc[i][j][r]);
                acc[i][j][r] = e;
                rs += e;
                E[(long)row * N + col] = f2bf(e);
            }
#pragma unroll
            for (int off = 1; off < 16; off <<= 1) rs += __shfl_xor(rs, off);
            if (l15 == 0) atomicAdd(rowsum + row, rs);
        }
    }

    if (!diag) {
#pragma unroll
        for (int j = 0; j < 2; ++j) {
            float cs = 0.f;
#pragma unroll
            for (int i = 0; i < 4; ++i)
#pragma unroll
                for (int r = 0; r < 4; ++r) cs += acc[i][j][r];
            cs += __shfl_xor(cs, 16);
            cs += __shfl_xor(cs, 32);
            if (q == 0) atomicAdd(rowsum + bn + wn * 32 + j * 16 + l15, cs);
        }

        unsigned short* tb = (unsigned short*)smem + wave * 2048;  // 4 KB/wave
        __syncthreads();
#pragma unroll
        for (int i = 0; i < 4; ++i) {
            const int lr0 = i * 16 + q * 4;
            const int blk = lr0 >> 3;
            const int half = (lr0 >> 2) & 1;
#pragma unroll
            for (int j = 0; j < 2; ++j) {
                const int lc = j * 16 + l15;
                union { unsigned short u[4]; uint2 v2; } pk;
#pragma unroll
                for (int r = 0; r < 4; ++r) pk.u[r] = f2bf(acc[i][j][r]);
                *(uint2*)&tb[lc * 64 + 8 * (blk ^ (lc & 7)) + 4 * half] = pk.v2;
            }
        }
        __syncthreads();

        const int gr0 = lane >> 3;
        const int cb  = lane & 7;
#pragma unroll
        for (int p = 0; p < 4; ++p) {
            const int gr = p * 8 + gr0;
            uint4 v = *(const uint4*)&tb[gr * 64 + 8 * (cb ^ (gr & 7))];
            *(uint4*)&E[(long)(bn + wn * 32 + gr) * N + bm + wm * 64 + cb * 8] = v;
        }
    }
}

// ---------------------------------------------------------------------------
// Kernel 3 (gemm_pv): out = (E/rowsum) x^T, bf16 (must be: absmax threshold
// 1.85e-5 forbids 8-bit P or V -- R7).  R8 change: pv is LDS-READ-bound
// (~196k cyc/CU of ds_read_b128 vs ~40k MFMA), so enlarge the wave tile to
// 128x64 (acc[8][4], 2.67 MFMA per fragment-read vs 2.0) on a 256x128 block
// tile: 25% fewer LDS reads + 25% fewer staging writes per FLOP.  512-block
// grid = exactly 2 co-resident blocks/CU (48 KB LDS, ~200 VGPR -> 2 w/SIMD;
// occupancy drop is safe per R5's neutrality result).
// ---------------------------------------------------------------------------
__global__ __launch_bounds__(256) void gemm_pv(const bf16* __restrict__ A,
                                               const bf16* __restrict__ B,
                                               float* __restrict__ C,
                                               const float* __restrict__ rowsum) {
    __shared__ bf16 As[PM * BK];  // 32 KB
    __shared__ bf16 Bs[PN * BK];  // 16 KB

    const int t    = threadIdx.x;
    const int lane = t & 63;
    const int wave = t >> 6;      // 0..3
    const int wm   = wave >> 1;   // 0..1  (128-row strip)
    const int wn   = wave & 1;    // 0..1  (64-col strip)
    const int bm   = blockIdx.y * PM;
    const int bn   = blockIdx.x * PN;

    floatx4 acc[8][4] = {};

    // staging, source-side XOR swizzle (verified conflict-free pattern)
    const int srow = t >> 3;                    // 0..31 (+32*i)
    const int skb  = (t & 7) ^ (srow & 7);
    const bf16* Ag = A + (long)(bm + srow) * N + skb * 8;
    const bf16* Bg = B + (long)(bn + srow) * N + skb * 8;
    bf16* Asl = As + t * 8;
    bf16* Bsl = Bs + t * 8;

    for (int k0 = 0; k0 < N; k0 += BK) {
#pragma unroll
        for (int i = 0; i < 8; ++i)   // A: 256 rows
            gld_lds16(Ag + (long)i * 32 * N + k0, Asl + i * 2048);
#pragma unroll
        for (int i = 0; i < 4; ++i)   // B: 128 rows
            gld_lds16(Bg + (long)i * 32 * N + k0, Bsl + i * 2048);
        __syncthreads();

        const int l15 = lane & 15;
        const int l7  = lane & 7;
        const int q   = lane >> 4;
#pragma unroll
        for (int kk = 0; kk < BK; kk += 32) {
            const int kw = (kk >> 3) + q;
            const int sw = kw ^ l7;
            bfrag a[8], b[4];
#pragma unroll
            for (int i = 0; i < 8; ++i)
                a[i] = *(const bfrag*)&As[((wm * 128 + i * 16 + l15) * 8 + sw) * 8];
#pragma unroll
            for (int j = 0; j < 4; ++j)
                b[j] = *(const bfrag*)&Bs[((wn * 64 + j * 16 + l15) * 8 + sw) * 8];
#pragma unroll
            for (int i = 0; i < 8; ++i)
#pragma unroll
                for (int j = 0; j < 4; ++j)
                    acc[i][j] = __builtin_amdgcn_mfma_f32_16x16x32_bf16(
                        a[i], b[j], acc[i][j], 0, 0, 0);
        }
        __syncthreads();
    }

    // epilogue: C/D layout col=lane&15, row=(lane>>4)*4+reg  [m89-verified]
    const int col0 = bn + wn * 64 + (lane & 15);
    const int row0 = bm + wm * 128 + (lane >> 4) * 4;
#pragma unroll
    for (int i = 0; i < 8; ++i) {
#pragma unroll
        for (int r = 0; r < 4; ++r) {
            const int row = row0 + i * 16 + r;
            const float inv = 1.0f / rowsum[row];
#pragma unroll
            for (int j = 0; j < 4; ++j)
                C[(long)row * N + col0 + j * 16] = acc[i][j][r] * inv;
        }
    }
}

// ---------------------------------------------------------------------------
extern "C" void kernel_launch(void* const* d_in, const int* in_sizes, int n_in,
                              void* d_out, int out_size, void* d_ws, size_t ws_size,
                              hipStream_t stream) {
    const float* in = (const float*)d_in[0];
    float* out = (float*)d_out;

    // ws: [rowsum 16KB] [xb 32MB bf16] [E 32MB bf16].
    // x8 (fp8, 16MB) lives in d_out -- dead until gemm_pv's final write,
    // which runs after gemm_sym has fully consumed it.
    float* rowsum = (float*)d_ws;
    bf16* xb = (bf16*)((char*)d_ws + 16384);
    unsigned short* E = (unsigned short*)((char*)d_ws + 16384 + (size_t)N * N * sizeof(bf16));
    uint8_t* x8 = (uint8_t*)d_out;

    cvt_scale<<<(N * (long)N) / (256 * 8), 256, 0, stream>>>(
        in, (unsigned short*)xb, x8, rowsum);

    // E = exp(mask(x x^T)) via 528 triangular fp8 tiles (32 K-iterations)
    gemm_sym<<<528, 512, 0, stream>>>(x8, E, rowsum);
    // out = (E / rowsum) x^T  -- 256x128 block tiles, 128x64 wave tiles
    dim3 grid(N / PN, N / PM);
    gemm_pv<<<grid, 256, 0, stream>>>((const bf16*)E, xb, out, rowsum);
}